// Round 8
// baseline (6650.005 us; speedup 1.0000x reference)
//
#include <hip/hip_runtime.h>
#include <hip/hip_bf16.h>
#include <stdint.h>

// Problem constants (fixed by setup_inputs)
#define BB 8
#define NN 16384
#define GG 1024
#define SS 32
#define BN (BB*NN)          // 131072

// Output offsets (elements, float32)
#define OFF_SIDX 0
#define OFF_SN   8192
#define OFF_SXYZ 770048     // 8192 + 8192*31*3
#define OFF_ORD  794624     // + 24576
#define OFF_INV  827392     // + 32768

// Workspace offsets (bytes)
#define WS_SIDX 0                    // int[8192]
#define WS_KNN  32768                // int[8192*32] = 1 MB
// FPS sync area OVERLAPS ws_knn (scratch until knn runs; knn fully
// overwrites it afterwards). cnt: u32 @ WS_KNN + b*64 (one line per batch,
// zeroed by hipMemsetAsync each launch). mail: u64 @ WS_KNN+512 + b*64
// (+ s*32 + k*8): plain atomic stores, fully overwritten before use.

typedef float v2f __attribute__((ext_vector_type(2)));
typedef unsigned long long u64x2 __attribute__((ext_vector_type(2)));

static __device__ __forceinline__ v2f vmin2(v2f a, v2f b) {
    v2f r; r.x = fminf(a.x, b.x); r.y = fminf(a.y, b.y); return r;
}
static __device__ __forceinline__ v2f vmax2(v2f a, v2f b) {
    v2f r; r.x = fmaxf(a.x, b.x); r.y = fmaxf(a.y, b.y); return r;
}

// DPP u32 max merge (fuses to v_max_u32_dpp). old=v, bound_ctrl=false =>
// lanes without a valid source keep v (idempotent merge).
template<int CTRL, int RM, int BM>
static __device__ __forceinline__ unsigned dpp_umax(unsigned v) {
    unsigned o = (unsigned)__builtin_amdgcn_update_dpp((int)v, (int)v, CTRL, RM, BM, false);
    return o > v ? o : v;
}

// DPP u64 min merge.
template<int CTRL, int RM, int BM>
static __device__ __forceinline__ uint64_t dpp_umin64(uint64_t v) {
    unsigned lo = (unsigned)v, hi = (unsigned)(v >> 32);
    unsigned olo = (unsigned)__builtin_amdgcn_update_dpp((int)lo, (int)lo, CTRL, RM, BM, false);
    unsigned ohi = (unsigned)__builtin_amdgcn_update_dpp((int)hi, (int)hi, CTRL, RM, BM, false);
    uint64_t o = ((uint64_t)ohi << 32) | olo;
    return o < v ? o : v;
}

// full-wave u64 min, result valid in lane 63
static __device__ __forceinline__ uint64_t wave_umin64(uint64_t v) {
    v = dpp_umin64<0x111, 0xf, 0xf>(v);   // row_shr:1
    v = dpp_umin64<0x112, 0xf, 0xf>(v);   // row_shr:2
    v = dpp_umin64<0x114, 0xf, 0xf>(v);   // row_shr:4
    v = dpp_umin64<0x118, 0xf, 0xf>(v);   // row_shr:8
    v = dpp_umin64<0x142, 0xa, 0xf>(v);   // row_bcast:15 -> rows 1,3
    v = dpp_umin64<0x143, 0xc, 0xf>(v);   // row_bcast:31 -> rows 2,3
    return v;
}

// broadcast u64 from (uniform) lane sl
static __device__ __forceinline__ uint64_t rdlane64(uint64_t v, int sl) {
    unsigned lo = (unsigned)__builtin_amdgcn_readlane((int)(unsigned)v, sl);
    unsigned hi = (unsigned)__builtin_amdgcn_readlane((int)(unsigned)(v >> 32), sl);
    return ((uint64_t)hi << 32) | lo;
}

// Monotone float->u32 map: preserves IEEE float ordering even for negatives
// (d2 = (cc+pp)-2dot can round to tiny negatives; numpy orders them lowest).
static __device__ __forceinline__ unsigned mono(float f) {
    unsigned u = __float_as_uint(f);
    return u ^ (unsigned)((((int)u) >> 31) | (int)0x80000000u);
}

// ---------------------------------------------------------------------------
// 1) FPS, R22: MULTI-CU. 4 blocks/batch (grid 32), 512 thr, 8 contiguous
//    pts/thread -> per-thread state 24 coord + 8 dist regs ~ 60 VGPR, which
//    is INSIDE the allocator's self-chosen budget (R1-R7 showed it spills
//    anything above ~92 no matter what hints we give; R6 proved pins hold
//    when demand fits). Per-CU per-step memory refetch worst-case is
//    shard-only (48KB, 4x less than before); best case zero (registers).
//    Cross-block step protocol (exact first-max preserved):
//      pack = (block_max_bits<<32) | (16383 - block_first_idx)  [u64]
//      t0: atomic store mail[b][g&1][k]; release fetch_add cnt[b]
//      all: spin acquire cnt[b] >= 4*g; read 4 mails; max-combine
//      sp = 16383 - (best & 0xffff)  -> winner idx; update dists vs coord[sp]
//    cnt is MONOTONE (no reset -> no reset race; memset 0 per launch).
//    2-slot mail: reads of slot s(g) all complete before any block passes
//    barrier g+1 < any overwrite at g+2. Blocks of batch b are bk%8==b ->
//    same XCD -> mailbox line stays in that XCD's L2 (fast atomics).
//    Sync space overlaps ws_knn (scratch until knn). Co-residency: 32 blocks
//    on 256 CUs. Claim path / formula / DPP structure = validated skeleton.
// ---------------------------------------------------------------------------
__global__ __launch_bounds__(512, 1)
void fps_kernel(const float* __restrict__ coord,
                int* __restrict__ ws_sidx,
                unsigned* __restrict__ cnt_arr,          // u32 @ b*16 (64B lines)
                unsigned long long* __restrict__ mail,   // u64 @ b*8 + s*4 + k
                float* __restrict__ out) {
#pragma clang fp contract(off)
    const int bk = blockIdx.x;
    const int b  = bk & 7;           // batch (same-XCD grouping: bk%8)
    const int k  = bk >> 3;          // shard 0..3
    const int t  = threadIdx.x;
    const int base = b * NN;
    const int so   = k << 12;        // shard offset, 4096 pts
    const int wave = t >> 6, lane = t & 63;

    __shared__ unsigned wv[8];       // per-wave max bits (8 waves)
    __shared__ unsigned win[2];      // packed block winner, parity-buffered

    // q0 = pts[0] (uniform scalar load)
    const float q0x = coord[3*base], q0y = coord[3*base+1], q0z = coord[3*base+2];

    // my 8 points: p_local = so + t*8 + j  (contiguous per thread)
    const float* my = coord + 3*(base + so + t*8);

    // pair j holds points 2j (x-slot), 2j+1 (y-slot); pin (demand fits budget)
    v2f px[4], py[4], pz[4];
#pragma unroll
    for (int j = 0; j < 4; j++) {
        px[j] = (v2f){my[6*j  ], my[6*j+3]};
        py[j] = (v2f){my[6*j+1], my[6*j+4]};
        pz[j] = (v2f){my[6*j+2], my[6*j+5]};
        asm volatile("" : "+v"(px[j]));
        asm volatile("" : "+v"(py[j]));
        asm volatile("" : "+v"(pz[j]));
    }

    v2f dist[4];
#pragma unroll
    for (int j = 0; j < 4; j++) {
        v2f dx = px[j] - (v2f){q0x,q0x};
        v2f dy = py[j] - (v2f){q0y,q0y};
        v2f dz = pz[j] - (v2f){q0z,q0z};
        dist[j] = (dx*dx + dy*dy) + dz*dz;   // == ref first update: min(inf,d2)
    }

    if (t == 0) {
        if (k == 0) {
            ws_sidx[b*GG] = base;            // selection 0 = index 0
            out[OFF_SIDX + b*GG] = (float)base;
        }
        win[0] = 0xffffffffu; win[1] = 0xffffffffu;
    }
    __syncthreads();

    for (int g = 1; g < GG; g++) {
        const int s = g & 1;
        // ---- per-thread max of current dist (value only)
        v2f m01 = vmax2(dist[0], dist[1]);
        v2f m23 = vmax2(dist[2], dist[3]);
        v2f m03 = vmax2(m01, m23);
        float bvf = fmaxf(m03.x, m03.y);
        unsigned lb = __float_as_uint(bvf);   // dist >= 0 -> raw-bit order OK
        // ---- wave max via DPP (value only; result in lane 63)
        unsigned r = lb;
        r = dpp_umax<0x111, 0xf, 0xf>(r);
        r = dpp_umax<0x112, 0xf, 0xf>(r);
        r = dpp_umax<0x114, 0xf, 0xf>(r);
        r = dpp_umax<0x118, 0xf, 0xf>(r);
        r = dpp_umax<0x142, 0xa, 0xf>(r);
        r = dpp_umax<0x143, 0xc, 0xf>(r);
        unsigned wmax = (unsigned)__builtin_amdgcn_readlane((int)r, 63);
        if (lane == 0) wv[wave] = wmax;
        __syncthreads();                      // B1
        if (t == 0) win[1 - s] = 0xffffffffu; // reset other slot for g+1
        // ---- block max: 8 wave winners, 3-level DPP within rows of 8
        unsigned x = wv[lane & 7];
        x = dpp_umax<0x111, 0xf, 0xf>(x);
        x = dpp_umax<0x112, 0xf, 0xf>(x);
        x = dpp_umax<0x114, 0xf, 0xf>(x);
        unsigned bmax = (unsigned)__builtin_amdgcn_readlane((int)x, 7);
        // ---- claim: exact block-first index = min (t*8 + jj) among matches
        if (lb == bmax) {
            int e = 7;
#pragma unroll
            for (int jj = 7; jj >= 0; jj--) {
                float v = (jj & 1) ? dist[jj >> 1].y : dist[jj >> 1].x;
                if (__float_as_uint(v) == bmax) e = jj;
            }
            atomicMin(&win[s], (unsigned)(t*8 + e));
        }
        __syncthreads();                      // B2: block winner resolved
        const unsigned pw = win[s];           // block-local [0,4096)
        const unsigned w_loc = (unsigned)so + pw;     // [0,16384)
        // pack: value desc primary, index asc secondary (exact first-max)
        const unsigned long long pack =
            (((unsigned long long)bmax) << 32) | (unsigned long long)(16383u - w_loc);
        if (t == 0) {
            __hip_atomic_store(&mail[b*8 + s*4 + k], pack,
                               __ATOMIC_RELAXED, __HIP_MEMORY_SCOPE_AGENT);
            __hip_atomic_fetch_add(&cnt_arr[b*16], 1u,
                                   __ATOMIC_RELEASE, __HIP_MEMORY_SCOPE_AGENT);
        }
        const unsigned target = 4u * (unsigned)g;
        while (__hip_atomic_load(&cnt_arr[b*16],
                                 __ATOMIC_ACQUIRE, __HIP_MEMORY_SCOPE_AGENT) < target) { }
        unsigned long long p0 = __hip_atomic_load(&mail[b*8 + s*4 + 0], __ATOMIC_RELAXED, __HIP_MEMORY_SCOPE_AGENT);
        unsigned long long p1 = __hip_atomic_load(&mail[b*8 + s*4 + 1], __ATOMIC_RELAXED, __HIP_MEMORY_SCOPE_AGENT);
        unsigned long long p2 = __hip_atomic_load(&mail[b*8 + s*4 + 2], __ATOMIC_RELAXED, __HIP_MEMORY_SCOPE_AGENT);
        unsigned long long p3 = __hip_atomic_load(&mail[b*8 + s*4 + 3], __ATOMIC_RELAXED, __HIP_MEMORY_SCOPE_AGENT);
        unsigned long long b01 = p0 > p1 ? p0 : p1;
        unsigned long long b23 = p2 > p3 ? p2 : p3;
        unsigned long long best = b01 > b23 ? b01 : b23;
        int sp = (int)(16383u - (unsigned)(best & 0xFFFFu));
        sp = __builtin_amdgcn_readfirstlane(sp);
        if (k == 0 && t == 0) {
            ws_sidx[b*GG + g] = base + sp;
            out[OFF_SIDX + b*GG + g] = (float)(base + sp);
        }
        // uniform (scalar) load of winner coords
        float qx = coord[3*(base+sp)];
        float qy = coord[3*(base+sp)+1];
        float qz = coord[3*(base+sp)+2];
        // ---- update: dist = min(dist, |p - q_g|^2), bit-exact
        v2f qvx = (v2f){qx,qx}, qvy = (v2f){qy,qy}, qvz = (v2f){qz,qz};
#pragma unroll
        for (int j = 0; j < 4; j++) {
            v2f dx = px[j] - qvx, dy = py[j] - qvy, dz = pz[j] - qvz;
            v2f d  = (dx*dx + dy*dy) + dz*dz;
            dist[j] = vmin2(dist[j], d);
        }
    }
}

// ---------------------------------------------------------------------------
// 2) kNN top-32: one wave per center, no LDS. Per-lane TOP-2 cache of packed
//    keys (mono(d2)<<14 | p): the scattered rescan of the winner's stripe
//    runs only when the winner's cache is empty (~7/32 rounds). mono() makes
//    key order == (d2 float order, index) lex == stable top_k semantics.
// ---------------------------------------------------------------------------
__global__ __launch_bounds__(64) void knn_kernel(const float* __restrict__ coord,
                                                 const int* __restrict__ ws_sidx,
                                                 int* __restrict__ ws_knn) {
#pragma clang fp contract(off)
    const int c = blockIdx.x;             // center 0..8191
    const int l = threadIdx.x;            // lane 0..63
    const int b = c >> 10;
    const int base = b * NN;
    const int sg = ws_sidx[c];            // global center index
    const float cx = coord[3*sg], cy = coord[3*sg+1], cz = coord[3*sg+2];
    const float cc = (cx*cx + cy*cy) + cz*cz;

    // phase 1: per-lane two smallest keys over stripe {l + 64*j}
    uint64_t k1 = ~0ull, k2 = ~0ull;
#pragma unroll 4
    for (int j = 0; j < 256; j++) {
        int p = l + (j << 6);
        float x = coord[3*(base+p)], y = coord[3*(base+p)+1], z = coord[3*(base+p)+2];
        float pp  = (x*x + y*y) + z*z;
        float dot = (cx*x + cy*y) + cz*z;
        float d2  = (cc + pp) - 2.0f*dot;             // ref formula exactly
        uint64_t key = (((uint64_t)mono(d2)) << 14) | (unsigned)p;
        if (key < k1)      { k2 = k1; k1 = key; }
        else if (key < k2) { k2 = key; }
    }

    uint64_t m0 = 0, m1 = 0, m2 = 0, m3 = 0;          // consumed bits, my stripe
    uint64_t cur = k1, nxt = k2;
    bool have_nxt = true;
    int res_p = 0;
    for (int k = 0; k < SS; k++) {
        // global argmin over per-lane current minima (value, then index)
        uint64_t wmin = wave_umin64(cur);
        uint64_t bkey = rdlane64(wmin, 63);           // scalar winner key
        const int bp = (int)(bkey & 16383u);          // winner point (scalar)
        const int w  = bp & 63;                       // winner lane / stripe
        const int e  = bp >> 6;                       // element within stripe
        if (l == k) res_p = bp;                       // lane k keeps k-th neighbor
        bool need_rescan = false;
        if (l == w) {                                 // mark consumed
            uint64_t bit = 1ull << (e & 63);
            int word = e >> 6;
            if      (word == 0) m0 |= bit;
            else if (word == 1) m1 |= bit;
            else if (word == 2) m2 |= bit;
            else                m3 |= bit;
            if (have_nxt) { cur = nxt; have_nxt = false; }
            else need_rescan = true;
        }
        if (__ballot(need_rescan)) {                  // wave-uniform rare path
            uint64_t w0 = rdlane64(m0, w), w1 = rdlane64(m1, w),
                     w2 = rdlane64(m2, w), w3 = rdlane64(m3, w);
            uint64_t best = ~0ull;
#pragma unroll
            for (int m = 0; m < 4; m++) {
                int e2 = l + (m << 6);
                uint64_t mw = (m == 0) ? w0 : ((m == 1) ? w1 : ((m == 2) ? w2 : w3));
                int p2 = w + (e2 << 6);
                float x = coord[3*(base+p2)], y = coord[3*(base+p2)+1], z = coord[3*(base+p2)+2];
                float pp  = (x*x + y*y) + z*z;
                float dot = (cx*x + cy*y) + cz*z;
                float d2  = (cc + pp) - 2.0f*dot;     // bit-exact recompute
                uint64_t key = (((uint64_t)mono(d2)) << 14) | (unsigned)p2;
                bool cons = (mw >> l) & 1ull;
                if (!cons && key < best) best = key;
            }
            best = wave_umin64(best);
            uint64_t rk = rdlane64(best, 63);
            if (l == w) cur = rk;                     // refreshed stripe-min
        }
    }
    if (l < SS) ws_knn[c * SS + l] = res_p;           // local point index
}

// ---------------------------------------------------------------------------
// 3) s_xyz gather
// ---------------------------------------------------------------------------
__global__ void sxyz_kernel(const float* __restrict__ coord,
                            const int* __restrict__ ws_sidx,
                            float* __restrict__ out) {
    int t = blockIdx.x * blockDim.x + threadIdx.x;
    if (t < 8192*3) {
        int i = t / 3, cmp = t - 3*i;
        out[OFF_SXYZ + t] = coord[3*ws_sidx[i] + cmp];
    }
}

// ---------------------------------------------------------------------------
// 4) s_n = coord[knn[1..31]] - center
// ---------------------------------------------------------------------------
__global__ void sn_kernel(const float* __restrict__ coord,
                          const int* __restrict__ ws_sidx,
                          const int* __restrict__ ws_knn,
                          float* __restrict__ out) {
#pragma clang fp contract(off)
    int t = blockIdx.x * blockDim.x + threadIdx.x;
    if (t < 8192*31*3) {
        int cmp = t % 3; int rem = t / 3;
        int j = rem % 31; int i = rem / 31;
        int b = i >> 10;
        int nb = ws_knn[i*SS + j + 1];                // skip neighbor 0 (self)
        int gidx = b*NN + nb;
        float v = coord[3*gidx + cmp] - coord[3*ws_sidx[i] + cmp];
        out[OFF_SN + t] = v;
    }
}

// ---------------------------------------------------------------------------
// 5) stable argsort per code row: REGISTER-BLOCKED bitonic sort of
//    (code<<13 | idx). Thread t owns the 8 contiguous elements i=8t..8t+7 in
//    registers; j>=8 passes swap 64B blocks via LDS. Unique keys => total
//    order == stable argsort (exact).
// ---------------------------------------------------------------------------
__global__ __launch_bounds__(1024) void sort_kernel(const int* __restrict__ ser,
                                                    const int* __restrict__ ws_sidx,
                                                    float* __restrict__ out) {
    __shared__ __align__(16) uint64_t keys[8192];     // 64 KB
    const int r = blockIdx.x, t = threadIdx.x;
    uint64_t e[8];
#pragma unroll
    for (int m = 0; m < 8; m++) {
        int i = t*8 + m;
        uint32_t code = (uint32_t)ser[r * BN + ws_sidx[i]];   // < 2^30
        e[m] = ((uint64_t)code << 13) | (uint32_t)i;          // unique keys
    }
#define CE(a, b, up) { uint64_t xa = e[a], xb = e[b]; \
                       if ((xa > xb) == (up)) { e[a] = xb; e[b] = xa; } }
    // k2 = 2 (up = ((m&2)==0)):
    CE(0,1,true) CE(2,3,false) CE(4,5,true) CE(6,7,false)
    // k2 = 4 (up = ((m&4)==0)):
    CE(0,2,true) CE(1,3,true) CE(4,6,false) CE(5,7,false)
    CE(0,1,true) CE(2,3,true) CE(4,5,false) CE(6,7,false)
    // k2 = 8 (up = ((t&1)==0), uniform in thread):
    {
        bool up = ((t & 1) == 0);
        CE(0,4,up) CE(1,5,up) CE(2,6,up) CE(3,7,up)
        CE(0,2,up) CE(1,3,up) CE(4,6,up) CE(5,7,up)
        CE(0,1,up) CE(2,3,up) CE(4,5,up) CE(6,7,up)
    }
    u64x2* kp = (u64x2*)keys;
    for (int k2 = 16; k2 <= 8192; k2 <<= 1) {
        const bool up = ((t & (k2 >> 3)) == 0);
        for (int j = k2 >> 1; j >= 8; j >>= 1) {
            // publish my current block
#pragma unroll
            for (int q = 0; q < 4; q++)
                kp[t*4 + q] = (u64x2){e[2*q], e[2*q+1]};
            __syncthreads();
            // read partner block (element m pairs with partner's element m)
            const int pt = t ^ (j >> 3);
            uint64_t pb[8];
#pragma unroll
            for (int q = 0; q < 4; q++) {
                u64x2 v = kp[pt*4 + q];
                pb[2*q] = v.x; pb[2*q+1] = v.y;
            }
            const bool lower = ((t & (j >> 3)) == 0);
            const bool keepmin = (lower == up);
#pragma unroll
            for (int m = 0; m < 8; m++) {
                uint64_t a = e[m], bq = pb[m];
                uint64_t mn = a < bq ? a : bq;
                uint64_t mx = a < bq ? bq : a;
                e[m] = keepmin ? mn : mx;
            }
            __syncthreads();   // all reads done before next pass overwrites
        }
        // tail j = 4, 2, 1 in-register (direction up, uniform)
        CE(0,4,up) CE(1,5,up) CE(2,6,up) CE(3,7,up)
        CE(0,2,up) CE(1,3,up) CE(4,6,up) CE(5,7,up)
        CE(0,1,up) CE(2,3,up) CE(4,5,up) CE(6,7,up)
    }
#undef CE
#pragma unroll
    for (int m = 0; m < 8; m++) {
        int k = t*8 + m;
        uint64_t key = e[m];
        int i = (int)(key & 8191u);
        out[OFF_ORD + r*8192 + k] = (float)i;
        out[OFF_INV + r*8192 + i] = (float)k;
    }
}

// ---------------------------------------------------------------------------
extern "C" void kernel_launch(void* const* d_in, const int* in_sizes, int n_in,
                              void* d_out, int out_size, void* d_ws, size_t ws_size,
                              hipStream_t stream) {
    const float* coord = (const float*)d_in[0];
    const int* ser = (const int*)d_in[1];
    float* out = (float*)d_out;
    char* ws = (char*)d_ws;
    int* ws_sidx = (int*)(ws + WS_SIDX);
    int* ws_knn  = (int*)(ws + WS_KNN);
    unsigned* cnt_arr = (unsigned*)(ws + WS_KNN);                      // 512 B
    unsigned long long* mail = (unsigned long long*)(ws + WS_KNN + 512); // 512 B

    // zero the monotone barrier counters (graph-capture-legal async fill)
    hipMemsetAsync(ws + WS_KNN, 0, 512, stream);

    hipLaunchKernelGGL(fps_kernel,  dim3(32),   dim3(512),  0, stream, coord, ws_sidx, cnt_arr, mail, out);
    hipLaunchKernelGGL(knn_kernel,  dim3(8192), dim3(64),   0, stream, coord, ws_sidx, ws_knn);
    hipLaunchKernelGGL(sxyz_kernel, dim3(96),   dim3(256),  0, stream, coord, ws_sidx, out);
    hipLaunchKernelGGL(sn_kernel,   dim3(2976), dim3(256),  0, stream, coord, ws_sidx, ws_knn, out);
    hipLaunchKernelGGL(sort_kernel, dim3(4),    dim3(1024), 0, stream, ser, ws_sidx, out);
}

// Round 9
// 1868.013 us; speedup vs baseline: 3.5599x; 3.5599x over previous
//
#include <hip/hip_runtime.h>
#include <hip/hip_bf16.h>
#include <stdint.h>

// Problem constants (fixed by setup_inputs)
#define BB 8
#define NN 16384
#define GG 1024
#define SS 32
#define BN (BB*NN)          // 131072

// Output offsets (elements, float32)
#define OFF_SIDX 0
#define OFF_SN   8192
#define OFF_SXYZ 770048     // 8192 + 8192*31*3
#define OFF_ORD  794624     // + 24576
#define OFF_INV  827392     // + 32768

// Workspace offsets (bytes)
#define WS_SIDX 0                    // int[8192]
#define WS_KNN  32768                // int[8192*32] = 1 MB

typedef float v2f __attribute__((ext_vector_type(2)));
typedef unsigned long long u64x2 __attribute__((ext_vector_type(2)));

static __device__ __forceinline__ v2f vmin2(v2f a, v2f b) {
    v2f r; r.x = fminf(a.x, b.x); r.y = fminf(a.y, b.y); return r;
}
static __device__ __forceinline__ v2f vmax2(v2f a, v2f b) {
    v2f r; r.x = fmaxf(a.x, b.x); r.y = fmaxf(a.y, b.y); return r;
}

// DPP u32 max merge (fuses to v_max_u32_dpp). old=v, bound_ctrl=false =>
// lanes without a valid source keep v (idempotent merge).
template<int CTRL, int RM, int BM>
static __device__ __forceinline__ unsigned dpp_umax(unsigned v) {
    unsigned o = (unsigned)__builtin_amdgcn_update_dpp((int)v, (int)v, CTRL, RM, BM, false);
    return o > v ? o : v;
}

// DPP u64 min merge.
template<int CTRL, int RM, int BM>
static __device__ __forceinline__ uint64_t dpp_umin64(uint64_t v) {
    unsigned lo = (unsigned)v, hi = (unsigned)(v >> 32);
    unsigned olo = (unsigned)__builtin_amdgcn_update_dpp((int)lo, (int)lo, CTRL, RM, BM, false);
    unsigned ohi = (unsigned)__builtin_amdgcn_update_dpp((int)hi, (int)hi, CTRL, RM, BM, false);
    uint64_t o = ((uint64_t)ohi << 32) | olo;
    return o < v ? o : v;
}

// full-wave u64 min, result valid in lane 63
static __device__ __forceinline__ uint64_t wave_umin64(uint64_t v) {
    v = dpp_umin64<0x111, 0xf, 0xf>(v);   // row_shr:1
    v = dpp_umin64<0x112, 0xf, 0xf>(v);   // row_shr:2
    v = dpp_umin64<0x114, 0xf, 0xf>(v);   // row_shr:4
    v = dpp_umin64<0x118, 0xf, 0xf>(v);   // row_shr:8
    v = dpp_umin64<0x142, 0xa, 0xf>(v);   // row_bcast:15 -> rows 1,3
    v = dpp_umin64<0x143, 0xc, 0xf>(v);   // row_bcast:31 -> rows 2,3
    return v;
}

// broadcast u64 from (uniform) lane sl
static __device__ __forceinline__ uint64_t rdlane64(uint64_t v, int sl) {
    unsigned lo = (unsigned)__builtin_amdgcn_readlane((int)(unsigned)v, sl);
    unsigned hi = (unsigned)__builtin_amdgcn_readlane((int)(unsigned)(v >> 32), sl);
    return ((uint64_t)hi << 32) | lo;
}

// Monotone float->u32 map: preserves IEEE float ordering even for negatives
// (d2 = (cc+pp)-2dot can round to tiny negatives; numpy orders them lowest).
static __device__ __forceinline__ unsigned mono(float f) {
    unsigned u = __float_as_uint(f);
    return u ^ (unsigned)((((int)u) >> 31) | (int)0x80000000u);
}

// ---------------------------------------------------------------------------
// 1) FPS: one block/batch, 1024 thr, 16 contiguous pts/thread (p = t*16+j).
//    R23: x,y pairs in LDS (128 KB, per-thread PRIVATE slots), z+dist in
//    registers, at 16 waves/CU.
//    Model from 8 rounds of measurement (per CU, per step, 196 KB set):
//      L1 refetch (R1/R2):            1.47 us/step   [measured]
//      LDS xy @ 2 waves/SIMD (R6):    1.66 us/step   [measured; no hiding]
//      registers:                     unreachable -- allocator caps ~64
//         (1024thr) / ~102 (512thr), ignores launch_bounds/waves_per_eu
//         (R1/R3/R4/R7); pins hold only when demand fits (R6)
//      cross-CU atomic sync (R8):     6.2 us/step    [measured; dead]
//    This config: same 256 ds_read_b64/CU/step as R6 (~1540 cyc LDS pipe)
//    but 4 waves/SIMD overlap LDS issue (1540) + VALU (~880/SIMD) + serial
//    chain (~400) -> ~0.7-0.9 us/step. Register demand scales down with
//    16 pts/thread: z 16 + dist 16 + temps ~30 = ~62 ~ the allocator's own
//    1024-thr budget, so nothing to fight. Each thread reads only its own
//    LDS slots (stride 8B across lanes = 2 lanes/bank = conflict-free).
//    Claim path / formula / barriers = R1/R2-verified skeleton, unchanged.
//    TELL: LDS ~131.6KB, VGPR 60-72, ~0.8us/step. If >=1.4us: spill/no-overlap.
// ---------------------------------------------------------------------------
__global__ __launch_bounds__(1024)
void fps_kernel(const float* __restrict__ coord,
                int* __restrict__ ws_sidx,
                float* __restrict__ out) {
#pragma clang fp contract(off)
    const int b = blockIdx.x;
    const int t = threadIdx.x;
    const int base = b * NN;
    const int wave = t >> 6, lane = t & 63;

    // 128 KB: per-thread private x/y pair slots (column layout: lane-adjacent)
    __shared__ __align__(16) v2f lds_xp[8192];   // [j*1024 + t]
    __shared__ __align__(16) v2f lds_yp[8192];
    __shared__ unsigned wv[16];       // per-wave max bits
    __shared__ unsigned win[2];       // packed winner p, double-buffered

    // q0 = pts[0] (uniform scalar load)
    const float q0x = coord[3*base], q0y = coord[3*base+1], q0z = coord[3*base+2];

    // thread-local flat view of my 48 floats (points t*16 .. t*16+15)
    const float* my = coord + 3*(base + t*16);

    // one-time load: pair j holds points 2j (x-slot) and 2j+1 (y-slot).
    // x,y -> my private LDS slots; z pinned in registers.
    v2f pz[8], dist[8];
#pragma unroll
    for (int j = 0; j < 8; j++) {
        v2f px = (v2f){my[6*j  ], my[6*j+3]};
        v2f py = (v2f){my[6*j+1], my[6*j+4]};
        pz[j]  = (v2f){my[6*j+2], my[6*j+5]};
        lds_xp[(j<<10) + t] = px;
        lds_yp[(j<<10) + t] = py;
        v2f dx = px - (v2f){q0x,q0x};
        v2f dy = py - (v2f){q0y,q0y};
        v2f dz = pz[j] - (v2f){q0z,q0z};
        dist[j] = (dx*dx + dy*dy) + dz*dz;   // == ref first update: min(inf,d2)
    }
#pragma unroll
    for (int j = 0; j < 8; j++) asm volatile("" : "+v"(pz[j]));

    if (t == 0) {
        ws_sidx[b*GG] = base;                 // selection 0 = index 0
        out[OFF_SIDX + b*GG] = (float)base;
        win[0] = 0xffffffffu; win[1] = 0xffffffffu;
    }
    __syncthreads();

    for (int g = 1; g < GG; g++) {
        const int s = g & 1;
        // ---- per-thread max of current dist (value only), pk tree
        v2f m01 = vmax2(dist[0], dist[1]);
        v2f m23 = vmax2(dist[2], dist[3]);
        v2f m45 = vmax2(dist[4], dist[5]);
        v2f m67 = vmax2(dist[6], dist[7]);
        v2f m07 = vmax2(vmax2(m01, m23), vmax2(m45, m67));
        float bvf = fmaxf(m07.x, m07.y);
        unsigned lb = __float_as_uint(bvf);   // local max as orderable bits
        // ---- wave max via DPP (value only; result in lane 63)
        unsigned r = lb;
        r = dpp_umax<0x111, 0xf, 0xf>(r);
        r = dpp_umax<0x112, 0xf, 0xf>(r);
        r = dpp_umax<0x114, 0xf, 0xf>(r);
        r = dpp_umax<0x118, 0xf, 0xf>(r);
        r = dpp_umax<0x142, 0xa, 0xf>(r);
        r = dpp_umax<0x143, 0xc, 0xf>(r);
        unsigned wmax = (unsigned)__builtin_amdgcn_readlane((int)r, 63);
        if (lane == 0) wv[wave] = wmax;
        __syncthreads();                      // B1
        if (t == 0) win[1 - s] = 0xffffffffu; // reset other slot for step g+1
        // ---- block max: 16 wave winners, 4-level DPP within rows of 16
        unsigned x = wv[lane & 15];
        x = dpp_umax<0x111, 0xf, 0xf>(x);
        x = dpp_umax<0x112, 0xf, 0xf>(x);
        x = dpp_umax<0x114, 0xf, 0xf>(x);
        x = dpp_umax<0x118, 0xf, 0xf>(x);
        unsigned bmax = (unsigned)__builtin_amdgcn_readlane((int)x, 15);
        // ---- claim: exact first-max index = min p = t*16 + jj (rare path)
        if (lb == bmax) {
            int e = 15;
#pragma unroll
            for (int jj = 15; jj >= 0; jj--) {
                float v = (jj & 1) ? dist[jj >> 1].y : dist[jj >> 1].x;
                if (__float_as_uint(v) == bmax) e = jj;
            }
            atomicMin(&win[s], (unsigned)(t*16 + e));
        }
        __syncthreads();                      // B2: winner resolved
        unsigned pw = win[s];
        int sp = __builtin_amdgcn_readfirstlane((int)pw);
        if (t == 0) {
            ws_sidx[b*GG + g] = base + sp;
            out[OFF_SIDX + b*GG + g] = (float)(base + sp);
        }
        // uniform (scalar) load of winner coords
        float qx = coord[3*(base+sp)];
        float qy = coord[3*(base+sp)+1];
        float qz = coord[3*(base+sp)+2];
        // ---- update: dist = min(dist, |p - q_g|^2), bit-exact.
        //      x,y stream from private LDS slots; z from registers.
        v2f qvx = (v2f){qx,qx}, qvy = (v2f){qy,qy}, qvz = (v2f){qz,qz};
#pragma unroll
        for (int j = 0; j < 8; j++) {
            v2f px = lds_xp[(j<<10) + t];
            v2f py = lds_yp[(j<<10) + t];
            v2f dx = px - qvx, dy = py - qvy, dz = pz[j] - qvz;
            v2f d  = (dx*dx + dy*dy) + dz*dz;
            dist[j] = vmin2(dist[j], d);
        }
    }
}

// ---------------------------------------------------------------------------
// 2) kNN top-32: one wave per center, no LDS. Per-lane TOP-2 cache of packed
//    keys (mono(d2)<<14 | p): the scattered rescan of the winner's stripe
//    runs only when the winner's cache is empty (~7/32 rounds). mono() makes
//    key order == (d2 float order, index) lex == stable top_k semantics.
// ---------------------------------------------------------------------------
__global__ __launch_bounds__(64) void knn_kernel(const float* __restrict__ coord,
                                                 const int* __restrict__ ws_sidx,
                                                 int* __restrict__ ws_knn) {
#pragma clang fp contract(off)
    const int c = blockIdx.x;             // center 0..8191
    const int l = threadIdx.x;            // lane 0..63
    const int b = c >> 10;
    const int base = b * NN;
    const int sg = ws_sidx[c];            // global center index
    const float cx = coord[3*sg], cy = coord[3*sg+1], cz = coord[3*sg+2];
    const float cc = (cx*cx + cy*cy) + cz*cz;

    // phase 1: per-lane two smallest keys over stripe {l + 64*j}
    uint64_t k1 = ~0ull, k2 = ~0ull;
#pragma unroll 4
    for (int j = 0; j < 256; j++) {
        int p = l + (j << 6);
        float x = coord[3*(base+p)], y = coord[3*(base+p)+1], z = coord[3*(base+p)+2];
        float pp  = (x*x + y*y) + z*z;
        float dot = (cx*x + cy*y) + cz*z;
        float d2  = (cc + pp) - 2.0f*dot;             // ref formula exactly
        uint64_t key = (((uint64_t)mono(d2)) << 14) | (unsigned)p;
        if (key < k1)      { k2 = k1; k1 = key; }
        else if (key < k2) { k2 = key; }
    }

    uint64_t m0 = 0, m1 = 0, m2 = 0, m3 = 0;          // consumed bits, my stripe
    uint64_t cur = k1, nxt = k2;
    bool have_nxt = true;
    int res_p = 0;
    for (int k = 0; k < SS; k++) {
        // global argmin over per-lane current minima (value, then index)
        uint64_t wmin = wave_umin64(cur);
        uint64_t bkey = rdlane64(wmin, 63);           // scalar winner key
        const int bp = (int)(bkey & 16383u);          // winner point (scalar)
        const int w  = bp & 63;                       // winner lane / stripe
        const int e  = bp >> 6;                       // element within stripe
        if (l == k) res_p = bp;                       // lane k keeps k-th neighbor
        bool need_rescan = false;
        if (l == w) {                                 // mark consumed
            uint64_t bit = 1ull << (e & 63);
            int word = e >> 6;
            if      (word == 0) m0 |= bit;
            else if (word == 1) m1 |= bit;
            else if (word == 2) m2 |= bit;
            else                m3 |= bit;
            if (have_nxt) { cur = nxt; have_nxt = false; }
            else need_rescan = true;
        }
        if (__ballot(need_rescan)) {                  // wave-uniform rare path
            uint64_t w0 = rdlane64(m0, w), w1 = rdlane64(m1, w),
                     w2 = rdlane64(m2, w), w3 = rdlane64(m3, w);
            uint64_t best = ~0ull;
#pragma unroll
            for (int m = 0; m < 4; m++) {
                int e2 = l + (m << 6);
                uint64_t mw = (m == 0) ? w0 : ((m == 1) ? w1 : ((m == 2) ? w2 : w3));
                int p2 = w + (e2 << 6);
                float x = coord[3*(base+p2)], y = coord[3*(base+p2)+1], z = coord[3*(base+p2)+2];
                float pp  = (x*x + y*y) + z*z;
                float dot = (cx*x + cy*y) + cz*z;
                float d2  = (cc + pp) - 2.0f*dot;     // bit-exact recompute
                uint64_t key = (((uint64_t)mono(d2)) << 14) | (unsigned)p2;
                bool cons = (mw >> l) & 1ull;
                if (!cons && key < best) best = key;
            }
            best = wave_umin64(best);
            uint64_t rk = rdlane64(best, 63);
            if (l == w) cur = rk;                     // refreshed stripe-min
        }
    }
    if (l < SS) ws_knn[c * SS + l] = res_p;           // local point index
}

// ---------------------------------------------------------------------------
// 3) s_xyz gather
// ---------------------------------------------------------------------------
__global__ void sxyz_kernel(const float* __restrict__ coord,
                            const int* __restrict__ ws_sidx,
                            float* __restrict__ out) {
    int t = blockIdx.x * blockDim.x + threadIdx.x;
    if (t < 8192*3) {
        int i = t / 3, cmp = t - 3*i;
        out[OFF_SXYZ + t] = coord[3*ws_sidx[i] + cmp];
    }
}

// ---------------------------------------------------------------------------
// 4) s_n = coord[knn[1..31]] - center
// ---------------------------------------------------------------------------
__global__ void sn_kernel(const float* __restrict__ coord,
                          const int* __restrict__ ws_sidx,
                          const int* __restrict__ ws_knn,
                          float* __restrict__ out) {
#pragma clang fp contract(off)
    int t = blockIdx.x * blockDim.x + threadIdx.x;
    if (t < 8192*31*3) {
        int cmp = t % 3; int rem = t / 3;
        int j = rem % 31; int i = rem / 31;
        int b = i >> 10;
        int nb = ws_knn[i*SS + j + 1];                // skip neighbor 0 (self)
        int gidx = b*NN + nb;
        float v = coord[3*gidx + cmp] - coord[3*ws_sidx[i] + cmp];
        out[OFF_SN + t] = v;
    }
}

// ---------------------------------------------------------------------------
// 5) stable argsort per code row: REGISTER-BLOCKED bitonic sort of
//    (code<<13 | idx). Thread t owns the 8 contiguous elements i=8t..8t+7 in
//    registers; j>=8 passes swap 64B blocks via LDS. Unique keys => total
//    order == stable argsort (exact).
// ---------------------------------------------------------------------------
__global__ __launch_bounds__(1024) void sort_kernel(const int* __restrict__ ser,
                                                    const int* __restrict__ ws_sidx,
                                                    float* __restrict__ out) {
    __shared__ __align__(16) uint64_t keys[8192];     // 64 KB
    const int r = blockIdx.x, t = threadIdx.x;
    uint64_t e[8];
#pragma unroll
    for (int m = 0; m < 8; m++) {
        int i = t*8 + m;
        uint32_t code = (uint32_t)ser[r * BN + ws_sidx[i]];   // < 2^30
        e[m] = ((uint64_t)code << 13) | (uint32_t)i;          // unique keys
    }
#define CE(a, b, up) { uint64_t xa = e[a], xb = e[b]; \
                       if ((xa > xb) == (up)) { e[a] = xb; e[b] = xa; } }
    // k2 = 2 (up = ((m&2)==0)):
    CE(0,1,true) CE(2,3,false) CE(4,5,true) CE(6,7,false)
    // k2 = 4 (up = ((m&4)==0)):
    CE(0,2,true) CE(1,3,true) CE(4,6,false) CE(5,7,false)
    CE(0,1,true) CE(2,3,true) CE(4,5,false) CE(6,7,false)
    // k2 = 8 (up = ((t&1)==0), uniform in thread):
    {
        bool up = ((t & 1) == 0);
        CE(0,4,up) CE(1,5,up) CE(2,6,up) CE(3,7,up)
        CE(0,2,up) CE(1,3,up) CE(4,6,up) CE(5,7,up)
        CE(0,1,up) CE(2,3,up) CE(4,5,up) CE(6,7,up)
    }
    u64x2* kp = (u64x2*)keys;
    for (int k2 = 16; k2 <= 8192; k2 <<= 1) {
        const bool up = ((t & (k2 >> 3)) == 0);
        for (int j = k2 >> 1; j >= 8; j >>= 1) {
            // publish my current block
#pragma unroll
            for (int q = 0; q < 4; q++)
                kp[t*4 + q] = (u64x2){e[2*q], e[2*q+1]};
            __syncthreads();
            // read partner block (element m pairs with partner's element m)
            const int pt = t ^ (j >> 3);
            uint64_t pb[8];
#pragma unroll
            for (int q = 0; q < 4; q++) {
                u64x2 v = kp[pt*4 + q];
                pb[2*q] = v.x; pb[2*q+1] = v.y;
            }
            const bool lower = ((t & (j >> 3)) == 0);
            const bool keepmin = (lower == up);
#pragma unroll
            for (int m = 0; m < 8; m++) {
                uint64_t a = e[m], bq = pb[m];
                uint64_t mn = a < bq ? a : bq;
                uint64_t mx = a < bq ? bq : a;
                e[m] = keepmin ? mn : mx;
            }
            __syncthreads();   // all reads done before next pass overwrites
        }
        // tail j = 4, 2, 1 in-register (direction up, uniform)
        CE(0,4,up) CE(1,5,up) CE(2,6,up) CE(3,7,up)
        CE(0,2,up) CE(1,3,up) CE(4,6,up) CE(5,7,up)
        CE(0,1,up) CE(2,3,up) CE(4,5,up) CE(6,7,up)
    }
#undef CE
#pragma unroll
    for (int m = 0; m < 8; m++) {
        int k = t*8 + m;
        uint64_t key = e[m];
        int i = (int)(key & 8191u);
        out[OFF_ORD + r*8192 + k] = (float)i;
        out[OFF_INV + r*8192 + i] = (float)k;
    }
}

// ---------------------------------------------------------------------------
extern "C" void kernel_launch(void* const* d_in, const int* in_sizes, int n_in,
                              void* d_out, int out_size, void* d_ws, size_t ws_size,
                              hipStream_t stream) {
    const float* coord = (const float*)d_in[0];
    const int* ser = (const int*)d_in[1];
    float* out = (float*)d_out;
    char* ws = (char*)d_ws;
    int* ws_sidx = (int*)(ws + WS_SIDX);
    int* ws_knn  = (int*)(ws + WS_KNN);

    hipLaunchKernelGGL(fps_kernel,  dim3(BB),   dim3(1024), 0, stream, coord, ws_sidx, out);
    hipLaunchKernelGGL(knn_kernel,  dim3(8192), dim3(64),   0, stream, coord, ws_sidx, ws_knn);
    hipLaunchKernelGGL(sxyz_kernel, dim3(96),   dim3(256),  0, stream, coord, ws_sidx, out);
    hipLaunchKernelGGL(sn_kernel,   dim3(2976), dim3(256),  0, stream, coord, ws_sidx, ws_knn, out);
    hipLaunchKernelGGL(sort_kernel, dim3(4),    dim3(1024), 0, stream, ser, ws_sidx, out);
}